// Round 1
// 2722.471 us; speedup vs baseline: 1.1006x; 1.1006x over previous
//
#include <hip/hip_runtime.h>
#include <hip/hip_bf16.h>

#define T_ 2048
#define H_ 4096
#define HQ_ 32
#define HKV_ 8
#define D_ 128
#define I_ 14336

typedef __attribute__((ext_vector_type(8))) short bf16x8;
typedef __attribute__((ext_vector_type(4))) float f32x4;

__device__ __forceinline__ float bf2f(short s) {
    return __uint_as_float(((unsigned int)(unsigned short)s) << 16);
}
__device__ __forceinline__ short f2bf(float f) {
    __hip_bfloat16 h = __float2bfloat16(f);
    unsigned short u;
    __builtin_memcpy(&u, &h, 2);
    return (short)u;
}

__device__ __forceinline__ void gload_lds16(const void* g, void* l) {
    __builtin_amdgcn_global_load_lds(
        (const __attribute__((address_space(1))) void*)g,
        (__attribute__((address_space(3))) void*)l, 16, 0, 0);
}

// ---------------------------------------------------------------- weight fp32 -> bf16
__global__ __launch_bounds__(256) void w2bf_kernel(
    const float* __restrict__ src, __hip_bfloat16* __restrict__ dst)
{
    size_t idx = ((size_t)blockIdx.x * 256 + threadIdx.x) * 8;
    float4 a = *(const float4*)(src + idx);
    float4 b = *(const float4*)(src + idx + 4);
    union { unsigned short u[8]; uint4 q; } o;
    o.u[0] = (unsigned short)f2bf(a.x);
    o.u[1] = (unsigned short)f2bf(a.y);
    o.u[2] = (unsigned short)f2bf(a.z);
    o.u[3] = (unsigned short)f2bf(a.w);
    o.u[4] = (unsigned short)f2bf(b.x);
    o.u[5] = (unsigned short)f2bf(b.y);
    o.u[6] = (unsigned short)f2bf(b.z);
    o.u[7] = (unsigned short)f2bf(b.w);
    *(uint4*)(dst + idx) = o.q;
}

// ---------------------------------------------------------------- RMSNorm
__global__ __launch_bounds__(256) void rmsnorm_kernel(
    const float* __restrict__ x, const float* __restrict__ w,
    __hip_bfloat16* __restrict__ out)
{
    int t = blockIdx.x, tid = threadIdx.x;
    const float4* xp = (const float4*)(x + (size_t)t * H_);
    float4 v[4];
    float ss = 0.f;
#pragma unroll
    for (int i = 0; i < 4; ++i) {
        v[i] = xp[i * 256 + tid];
        ss += v[i].x * v[i].x + v[i].y * v[i].y + v[i].z * v[i].z + v[i].w * v[i].w;
    }
#pragma unroll
    for (int off = 32; off; off >>= 1) ss += __shfl_xor(ss, off, 64);
    __shared__ float red[4];
    int wave = tid >> 6, lane = tid & 63;
    if (lane == 0) red[wave] = ss;
    __syncthreads();
    float scale = rsqrtf((red[0] + red[1] + red[2] + red[3]) * (1.0f / H_) + 1e-5f);
    const float4* wp = (const float4*)w;
    uint2* op = (uint2*)(out + (size_t)t * H_);
#pragma unroll
    for (int i = 0; i < 4; ++i) {
        float4 wv = wp[i * 256 + tid];
        union { unsigned short u[4]; uint2 d; } o;
        o.u[0] = (unsigned short)f2bf(v[i].x * scale * wv.x);
        o.u[1] = (unsigned short)f2bf(v[i].y * scale * wv.y);
        o.u[2] = (unsigned short)f2bf(v[i].z * scale * wv.z);
        o.u[3] = (unsigned short)f2bf(v[i].w * scale * wv.w);
        op[i * 256 + tid] = o.d;
    }
}

// ---------------------------------------------------------------- GEMM (m97 structure)
// C[m][n] = sum_k A[m][k] * B[n][k], A and B both bf16.
// 128x128 tile, BK=32, linear LDS, global_load_lds width=16, XCD-swizzled blocks.
// RESADD=0: C bf16.  RESADD=1: C fp32 = acc + res.
template <int RESADD>
__global__ __launch_bounds__(256) void gemm_kernel(
    const __hip_bfloat16* __restrict__ A, const __hip_bfloat16* __restrict__ B,
    void* __restrict__ Cout, const float* __restrict__ res,
    int M, int N, int K)
{
    constexpr int BM = 128, BN = 128, BK = 32;
    __shared__ __align__(16) __hip_bfloat16 As[BM * BK];
    __shared__ __align__(16) __hip_bfloat16 Bs[BN * BK];
    int tid = threadIdx.x;
    int wave = tid >> 6, lane = tid & 63, ln = lane & 15, quad = lane >> 4;
    int wr = wave >> 1, wc = wave & 1;

    // bijective XCD-aware swizzle (m204): contiguous chunk of block ids per XCD,
    // m-fastest inside the chunk so the 16 blocks sharing a B-panel are adjacent.
    int nwg = gridDim.x * gridDim.y;
    int orig = blockIdx.y * gridDim.x + blockIdx.x;
    int xcd = orig & 7, loc = orig >> 3;
    int qq = nwg >> 3, rr = nwg & 7;
    int swz = (xcd < rr ? xcd * (qq + 1) : rr * (qq + 1) + (xcd - rr) * qq) + loc;
    int m0 = (swz % gridDim.x) * BM;
    int n0 = (swz / gridDim.x) * BN;

    // staging: 4 x global_load_lds(16B) per thread per K-step.
    // chunk c (=tid or tid+256) -> LDS byte c*16 -> row c/4, 8-elem slot c%4
    int row = tid >> 2, slot = tid & 3;
    const __hip_bfloat16* ga0 = A + (size_t)(m0 + row) * K + slot * 8;
    const __hip_bfloat16* ga1 = A + (size_t)(m0 + 64 + row) * K + slot * 8;
    const __hip_bfloat16* gb0 = B + (size_t)(n0 + row) * K + slot * 8;
    const __hip_bfloat16* gb1 = B + (size_t)(n0 + 64 + row) * K + slot * 8;
    __hip_bfloat16* la0 = As + tid * 8;
    __hip_bfloat16* la1 = As + 2048 + tid * 8;
    __hip_bfloat16* lb0 = Bs + tid * 8;
    __hip_bfloat16* lb1 = Bs + 2048 + tid * 8;

    f32x4 acc[4][4] = {};

    for (int k0 = 0; k0 < K; k0 += BK) {
        __syncthreads();   // previous iter's ds_reads done before overwrite
        gload_lds16(ga0, la0);
        gload_lds16(ga1, la1);
        gload_lds16(gb0, lb0);
        gload_lds16(gb1, lb1);
        ga0 += BK; ga1 += BK; gb0 += BK; gb1 += BK;
        __syncthreads();   // compiler drains vmcnt(0) here -> tile visible

        bf16x8 af[4], bfr[4];
#pragma unroll
        for (int i = 0; i < 4; ++i)
            af[i] = *(const bf16x8*)&As[(wr * 64 + i * 16 + ln) * BK + quad * 8];
#pragma unroll
        for (int j = 0; j < 4; ++j)
            bfr[j] = *(const bf16x8*)&Bs[(wc * 64 + j * 16 + ln) * BK + quad * 8];
#pragma unroll
        for (int i = 0; i < 4; ++i)
#pragma unroll
            for (int j = 0; j < 4; ++j)
                acc[i][j] = __builtin_amdgcn_mfma_f32_16x16x32_bf16(af[i], bfr[j], acc[i][j], 0, 0, 0);
    }

#pragma unroll
    for (int i = 0; i < 4; ++i)
#pragma unroll
        for (int j = 0; j < 4; ++j)
#pragma unroll
            for (int r = 0; r < 4; ++r) {
                int row_ = m0 + wr * 64 + i * 16 + quad * 4 + r;
                int col_ = n0 + wc * 64 + j * 16 + ln;
                if (RESADD) {
                    ((float*)Cout)[(size_t)row_ * N + col_] =
                        acc[i][j][r] + res[(size_t)row_ * N + col_];
                } else {
                    ((__hip_bfloat16*)Cout)[(size_t)row_ * N + col_] =
                        __float2bfloat16(acc[i][j][r]);
                }
            }
}

// ---------------------------------------------------------------- RoPE (in place on q and k)
__global__ __launch_bounds__(64) void rope_kernel(
    __hip_bfloat16* __restrict__ q, __hip_bfloat16* __restrict__ k,
    const int* __restrict__ pos)
{
    int t = blockIdx.x, h = blockIdx.y, i = threadIdx.x;
    float p = (float)pos[t];
    float inv = powf(500000.0f, -(float)i * (1.0f / 64.0f));
    float s, c;
    sincosf(p * inv, &s, &c);
    __hip_bfloat16* base = (h < HQ_) ? (q + ((size_t)t * HQ_ + h) * D_)
                                     : (k + ((size_t)t * HKV_ + (h - HQ_)) * D_);
    float x1 = bf2f(*(short*)&base[i]);
    float x2 = bf2f(*(short*)&base[i + 64]);
    base[i]      = __float2bfloat16(x1 * c - x2 * s);
    base[i + 64] = __float2bfloat16(x2 * c + x1 * s);
}

// ---------------------------------------------------------------- Flash attention
// grid (qtile=32, head=32), block 256 (4 waves); wave handles 16 q rows.
__global__ __launch_bounds__(256) void attn_kernel(
    const __hip_bfloat16* __restrict__ Q,  // T x HQ x D
    const __hip_bfloat16* __restrict__ K,  // T x HKV x D
    const __hip_bfloat16* __restrict__ V,  // T x HKV x D
    __hip_bfloat16* __restrict__ O)        // T x (HQ*D)
{
    constexpr float scale = 0.08838834764831845f;  // 1/sqrt(128)
    int qtile = blockIdx.x, hq = blockIdx.y, hkv = hq >> 2;
    int tid = threadIdx.x;
    int wave = tid >> 6, lane = tid & 63, ln = lane & 15, quad = lane >> 4;
    int q0 = qtile * 64;

    __shared__ __align__(16) __hip_bfloat16 Kt[32 * 136];   // K rows, row-major, pad
    __shared__ __align__(16) __hip_bfloat16 Vt[128 * 40];   // V^T: [dim][key], pad
    __shared__ __align__(16) __hip_bfloat16 Pb[4][16 * 40]; // per-wave P

    bf16x8 qf[4];
    {
        const __hip_bfloat16* qp = Q + ((size_t)(q0 + wave * 16 + ln) * HQ_ + hq) * D_;
#pragma unroll
        for (int kc = 0; kc < 4; ++kc)
            qf[kc] = *(const bf16x8*)(qp + kc * 32 + quad * 8);
    }

    f32x4 o_acc[8] = {};
    float m_run[4] = { -3e38f, -3e38f, -3e38f, -3e38f };
    float l_run[4] = { 0.f, 0.f, 0.f, 0.f };

    int nkt = (q0 + 64) / 32;  // causal tile count
    int sr = tid >> 3, sseg = tid & 7;
    for (int kt = 0; kt < nkt; ++kt) {
        int k0 = kt * 32;
        {
            const __hip_bfloat16* kp = K + ((size_t)(k0 + sr) * HKV_ + hkv) * D_ + sseg * 16;
            uint4 k01 = ((const uint4*)kp)[0], k23 = ((const uint4*)kp)[1];
            *(uint4*)&Kt[sr * 136 + sseg * 16]     = k01;
            *(uint4*)&Kt[sr * 136 + sseg * 16 + 8] = k23;
            const __hip_bfloat16* vp = V + ((size_t)(k0 + sr) * HKV_ + hkv) * D_ + sseg * 16;
            union { uint4 q[2]; __hip_bfloat16 h[16]; } vv;
            vv.q[0] = ((const uint4*)vp)[0];
            vv.q[1] = ((const uint4*)vp)[1];
#pragma unroll
            for (int i = 0; i < 16; ++i) Vt[(sseg * 16 + i) * 40 + sr] = vv.h[i];
        }
        __syncthreads();

        f32x4 s_acc[2] = {};
#pragma unroll
        for (int ct = 0; ct < 2; ++ct)
#pragma unroll
            for (int kc = 0; kc < 4; ++kc) {
                bf16x8 kf = *(const bf16x8*)&Kt[(ct * 16 + ln) * 136 + kc * 32 + quad * 8];
                s_acc[ct] = __builtin_amdgcn_mfma_f32_16x16x32_bf16(qf[kc], kf, s_acc[ct], 0, 0, 0);
            }

        float pv[2][4], tmax[4];
#pragma unroll
        for (int r = 0; r < 4; ++r) {
            int qr = q0 + wave * 16 + quad * 4 + r;
            float s0 = s_acc[0][r] * scale;
            float s1 = s_acc[1][r] * scale;
            if (k0 + ln > qr) s0 = -1e30f;
            if (k0 + 16 + ln > qr) s1 = -1e30f;
            pv[0][r] = s0; pv[1][r] = s1;
            tmax[r] = fmaxf(s0, s1);
        }
#pragma unroll
        for (int off = 1; off < 16; off <<= 1)
#pragma unroll
            for (int r = 0; r < 4; ++r)
                tmax[r] = fmaxf(tmax[r], __shfl_xor(tmax[r], off, 64));

        float alpha[4], tsum[4];
#pragma unroll
        for (int r = 0; r < 4; ++r) {
            float mn = fmaxf(m_run[r], tmax[r]);
            alpha[r] = __expf(m_run[r] - mn);
            m_run[r] = mn;
            float p0 = __expf(pv[0][r] - mn);
            float p1 = __expf(pv[1][r] - mn);
            pv[0][r] = p0; pv[1][r] = p1;
            tsum[r] = p0 + p1;
        }
#pragma unroll
        for (int off = 1; off < 16; off <<= 1)
#pragma unroll
            for (int r = 0; r < 4; ++r)
                tsum[r] += __shfl_xor(tsum[r], off, 64);
#pragma unroll
        for (int r = 0; r < 4; ++r) l_run[r] = l_run[r] * alpha[r] + tsum[r];
#pragma unroll
        for (int nt = 0; nt < 8; ++nt)
#pragma unroll
            for (int r = 0; r < 4; ++r) o_acc[nt][r] *= alpha[r];

#pragma unroll
        for (int r = 0; r < 4; ++r) {
            Pb[wave][(quad * 4 + r) * 40 + ln]      = __float2bfloat16(pv[0][r]);
            Pb[wave][(quad * 4 + r) * 40 + 16 + ln] = __float2bfloat16(pv[1][r]);
        }
        asm volatile("s_waitcnt lgkmcnt(0)" ::: "memory");

        bf16x8 pf = *(const bf16x8*)&Pb[wave][ln * 40 + quad * 8];
#pragma unroll
        for (int nt = 0; nt < 8; ++nt) {
            bf16x8 vf = *(const bf16x8*)&Vt[(nt * 16 + ln) * 40 + quad * 8];
            o_acc[nt] = __builtin_amdgcn_mfma_f32_16x16x32_bf16(pf, vf, o_acc[nt], 0, 0, 0);
        }
        __syncthreads();
    }

    float inv_l[4];
#pragma unroll
    for (int r = 0; r < 4; ++r) inv_l[r] = 1.0f / l_run[r];
#pragma unroll
    for (int nt = 0; nt < 8; ++nt)
#pragma unroll
        for (int r = 0; r < 4; ++r) {
            int qr = q0 + wave * 16 + quad * 4 + r;
            O[(size_t)qr * H_ + hq * D_ + nt * 16 + ln] =
                __float2bfloat16(o_acc[nt][r] * inv_l[r]);
        }
}

// ---------------------------------------------------------------- silu(gate)*up -> gate
__global__ __launch_bounds__(256) void silu_mul_kernel(
    __hip_bfloat16* __restrict__ gate, const __hip_bfloat16* __restrict__ up)
{
    size_t idx = (size_t)blockIdx.x * 256 + threadIdx.x;
    bf16x8 g = ((const bf16x8*)gate)[idx];
    bf16x8 u = ((const bf16x8*)up)[idx];
    bf16x8 o;
#pragma unroll
    for (int j = 0; j < 8; ++j) {
        float gf = bf2f(g[j]);
        float uf = bf2f(u[j]);
        float r = gf / (1.0f + __expf(-gf)) * uf;
        o[j] = f2bf(r);
    }
    ((bf16x8*)gate)[idx] = o;
}

// ---------------------------------------------------------------- launch
extern "C" void kernel_launch(void* const* d_in, const int* in_sizes, int n_in,
                              void* d_out, int out_size, void* d_ws, size_t ws_size,
                              hipStream_t stream) {
    const float* x_in   = (const float*)d_in[0];
    const int*   pos    = (const int*)d_in[1];
    const float* w_q    = (const float*)d_in[2];
    const float* w_k    = (const float*)d_in[3];
    const float* w_v    = (const float*)d_in[4];
    const float* w_o    = (const float*)d_in[5];
    const float* w_gate = (const float*)d_in[6];
    const float* w_up   = (const float*)d_in[7];
    const float* w_down = (const float*)d_in[8];
    const float* rms1   = (const float*)d_in[9];
    const float* rms2   = (const float*)d_in[10];
    float* out = (float*)d_out;

    char* ws = (char*)d_ws;
    size_t off = 0;
    auto alloc = [&](size_t bytes) {
        void* p = ws + off;
        off += (bytes + 255) & ~(size_t)255;
        return p;
    };
    __hip_bfloat16* hb   = (__hip_bfloat16*)alloc((size_t)T_ * H_ * 2);        // h, then attn out
    __hip_bfloat16* qb   = (__hip_bfloat16*)alloc((size_t)T_ * HQ_ * D_ * 2);  // q, then h2
    __hip_bfloat16* kb   = (__hip_bfloat16*)alloc((size_t)T_ * HKV_ * D_ * 2);
    __hip_bfloat16* vb   = (__hip_bfloat16*)alloc((size_t)T_ * HKV_ * D_ * 2);
    float*          x1   = (float*)alloc((size_t)T_ * H_ * 4);
    __hip_bfloat16* gate = (__hip_bfloat16*)alloc((size_t)T_ * I_ * 2);        // gate, then m
    __hip_bfloat16* up   = (__hip_bfloat16*)alloc((size_t)T_ * I_ * 2);
    // bf16 weight copies
    __hip_bfloat16* wqb  = (__hip_bfloat16*)alloc((size_t)H_ * H_ * 2);
    __hip_bfloat16* wkb  = (__hip_bfloat16*)alloc((size_t)HKV_ * D_ * H_ * 2);
    __hip_bfloat16* wvb  = (__hip_bfloat16*)alloc((size_t)HKV_ * D_ * H_ * 2);
    __hip_bfloat16* wob  = (__hip_bfloat16*)alloc((size_t)H_ * H_ * 2);
    __hip_bfloat16* wgb  = (__hip_bfloat16*)alloc((size_t)I_ * H_ * 2);
    __hip_bfloat16* wub  = (__hip_bfloat16*)alloc((size_t)I_ * H_ * 2);
    __hip_bfloat16* wdb  = (__hip_bfloat16*)alloc((size_t)H_ * I_ * 2);

    auto cvt = [&](const float* s, __hip_bfloat16* d, size_t n) {
        w2bf_kernel<<<(unsigned)(n / 2048), 256, 0, stream>>>(s, d);
    };
    cvt(w_q,    wqb, (size_t)H_ * H_);
    cvt(w_k,    wkb, (size_t)HKV_ * D_ * H_);
    cvt(w_v,    wvb, (size_t)HKV_ * D_ * H_);
    cvt(w_o,    wob, (size_t)H_ * H_);
    cvt(w_gate, wgb, (size_t)I_ * H_);
    cvt(w_up,   wub, (size_t)I_ * H_);
    cvt(w_down, wdb, (size_t)H_ * I_);

    rmsnorm_kernel<<<T_, 256, 0, stream>>>(x_in, rms1, hb);
    gemm_kernel<0><<<dim3(16, 32), 256, 0, stream>>>(hb, wqb, qb, nullptr, T_, H_, H_);
    gemm_kernel<0><<<dim3(16, 8), 256, 0, stream>>>(hb, wkb, kb, nullptr, T_, HKV_ * D_, H_);
    gemm_kernel<0><<<dim3(16, 8), 256, 0, stream>>>(hb, wvb, vb, nullptr, T_, HKV_ * D_, H_);
    rope_kernel<<<dim3(T_, HQ_ + HKV_), 64, 0, stream>>>(qb, kb, pos);
    attn_kernel<<<dim3(32, 32), 256, 0, stream>>>(qb, kb, vb, hb);
    gemm_kernel<1><<<dim3(16, 32), 256, 0, stream>>>(hb, wob, x1, x_in, T_, H_, H_);
    rmsnorm_kernel<<<T_, 256, 0, stream>>>(x1, rms2, qb);
    gemm_kernel<0><<<dim3(16, 112), 256, 0, stream>>>(qb, wgb, gate, nullptr, T_, I_, H_);
    gemm_kernel<0><<<dim3(16, 112), 256, 0, stream>>>(qb, wub, up, nullptr, T_, I_, H_);
    silu_mul_kernel<<<(T_ * I_ / 8) / 256, 256, 0, stream>>>(gate, up);
    gemm_kernel<1><<<dim3(16, 32), 256, 0, stream>>>(gate, wdb, out, x1, T_, H_, I_);
}